// Round 1
// baseline (6333.186 us; speedup 1.0000x reference)
//
#include <hip/hip_runtime.h>

#define N_NODES 50000
#define N_EDGES 800000
#define N_GRAPHS 512
#define DIM 128
#define NLAYERS 4
#define BN_EPS 1e-5f

typedef float f32x4 __attribute__((ext_vector_type(4)));
typedef short bf16x8 __attribute__((ext_vector_type(8)));

__device__ __forceinline__ short f2bs(float f) {
    union { float f; unsigned u; } v; v.f = f;
    unsigned r = v.u + 0x7FFFu + ((v.u >> 16) & 1u);
    return (short)(r >> 16);
}
__device__ __forceinline__ unsigned enc_f(float f) {
    union { float f; unsigned u; } v; v.f = f;
    return (v.u & 0x80000000u) ? ~v.u : (v.u | 0x80000000u);
}
__device__ __forceinline__ float dec_f(unsigned k) {
    union { unsigned u; float f; } v;
    v.u = (k & 0x80000000u) ? (k ^ 0x80000000u) : ~k;
    return v.f;
}

// ---------------- init: pool keys to enc(-inf), stats to 0 ----------------
__global__ void k_init(unsigned* __restrict__ pool, float* __restrict__ stats) {
    int i = blockIdx.x * 256 + threadIdx.x;
    if (i < 5 * N_GRAPHS * DIM) pool[i] = 0x007FFFFFu;  // enc(-inf)
    if (i < 256) stats[i] = 0.f;
}

// ---------------- prep: W1s,W2s (fp32 row-major) -> wt[8][n][k] bf16 (W^T) ----------------
__global__ void k_prep_w(const float* __restrict__ W1s, const float* __restrict__ W2s,
                         short* __restrict__ wt) {
    int i = blockIdx.x * 256 + threadIdx.x;  // 8*16384
    int m = i >> 14;
    int r = i & 16383;
    int n = r >> 7, k = r & 127;
    const float* W = (m < 4) ? (W1s + m * 16384) : (W2s + (m - 4) * 16384);
    wt[i] = f2bs(W[k * DIM + n]);
}

// ---------------- Z = h ; pool[0] max= h ----------------
__global__ void k_copy_pool(const float* __restrict__ h, const int* __restrict__ gids,
                            float* __restrict__ Z, unsigned* __restrict__ pool) {
    int t = blockIdx.x * 256 + threadIdx.x;  // N_NODES*32
    int node = t >> 5, c4 = (t & 31) << 2;
    f32x4 v = *(const f32x4*)(h + node * DIM + c4);
    *(f32x4*)(Z + node * DIM + c4) = v;
    int g = gids[node];
    unsigned* p = pool + g * DIM + c4;
    atomicMax(p + 0, enc_f(v.x));
    atomicMax(p + 1, enc_f(v.y));
    atomicMax(p + 2, enc_f(v.z));
    atomicMax(p + 3, enc_f(v.w));
}

// ---------------- Z[dst] += h[src] over edges ----------------
__global__ void k_scatter(const float* __restrict__ h, const int* __restrict__ src,
                          const int* __restrict__ dst, float* __restrict__ Z) {
    int t = blockIdx.x * 256 + threadIdx.x;  // N_EDGES*32
    int e = t >> 5, c4 = (t & 31) << 2;
    int s = src[e], d = dst[e];
    f32x4 v = *(const f32x4*)(h + s * DIM + c4);
    float* z = Z + d * DIM + c4;
    atomicAdd(z + 0, v.x);
    atomicAdd(z + 1, v.y);
    atomicAdd(z + 2, v.z);
    atomicAdd(z + 3, v.w);
}

// ---------------- OUT = f(X) @ W  (+ column sum/sumsq stats) ----------------
// f = identity (gemm1) or relu(a*x+b) per input column (gemm2).
// Wave computes 16 rows x 128 cols. b-frags (W^T bf16) preloaded to registers.
template <bool XFORM>
__global__ __launch_bounds__(256) void k_gemm(const float* __restrict__ X,
                                              const short* __restrict__ wt,
                                              const float* __restrict__ ab,
                                              float* __restrict__ OUT,
                                              float* __restrict__ stats) {
    const int lane = threadIdx.x & 63;
    const int wid = threadIdx.x >> 6;
    const int ln15 = lane & 15;
    const int q = lane >> 4;  // 0..3

    bf16x8 bfr[8][4];
#pragma unroll
    for (int tl = 0; tl < 8; tl++) {
        int n = tl * 16 + ln15;
#pragma unroll
        for (int s = 0; s < 4; s++)
            bfr[tl][s] = *(const bf16x8*)(wt + n * DIM + s * 32 + q * 8);
    }
    float sac[8], qac[8];
#pragma unroll
    for (int t = 0; t < 8; t++) { sac[t] = 0.f; qac[t] = 0.f; }

    const int wave_global = blockIdx.x * 4 + wid;
    const int nwaves = gridDim.x * 4;
    for (int tile = wave_global; tile < N_NODES / 16; tile += nwaves) {
        const float* xrow = X + (tile * 16 + ln15) * DIM;
        f32x4 acc[8];
#pragma unroll
        for (int t = 0; t < 8; t++) acc[t] = (f32x4){0.f, 0.f, 0.f, 0.f};
#pragma unroll
        for (int s = 0; s < 4; s++) {
            int k0 = s * 32 + q * 8;
            f32x4 x0 = *(const f32x4*)(xrow + k0);
            f32x4 x1 = *(const f32x4*)(xrow + k0 + 4);
            if (XFORM) {
                f32x4 a0 = *(const f32x4*)(ab + k0);
                f32x4 a1 = *(const f32x4*)(ab + k0 + 4);
                f32x4 b0 = *(const f32x4*)(ab + DIM + k0);
                f32x4 b1 = *(const f32x4*)(ab + DIM + k0 + 4);
                x0.x = fmaxf(a0.x * x0.x + b0.x, 0.f);
                x0.y = fmaxf(a0.y * x0.y + b0.y, 0.f);
                x0.z = fmaxf(a0.z * x0.z + b0.z, 0.f);
                x0.w = fmaxf(a0.w * x0.w + b0.w, 0.f);
                x1.x = fmaxf(a1.x * x1.x + b1.x, 0.f);
                x1.y = fmaxf(a1.y * x1.y + b1.y, 0.f);
                x1.z = fmaxf(a1.z * x1.z + b1.z, 0.f);
                x1.w = fmaxf(a1.w * x1.w + b1.w, 0.f);
            }
            bf16x8 afr;
            afr[0] = f2bs(x0.x); afr[1] = f2bs(x0.y);
            afr[2] = f2bs(x0.z); afr[3] = f2bs(x0.w);
            afr[4] = f2bs(x1.x); afr[5] = f2bs(x1.y);
            afr[6] = f2bs(x1.z); afr[7] = f2bs(x1.w);
#pragma unroll
            for (int t = 0; t < 8; t++)
                acc[t] = __builtin_amdgcn_mfma_f32_16x16x32_bf16(afr, bfr[t][s], acc[t], 0, 0, 0);
        }
#pragma unroll
        for (int t = 0; t < 8; t++) {
            float s_l = 0.f, q_l = 0.f;
#pragma unroll
            for (int r = 0; r < 4; r++) {
                float v = acc[t][r];
                OUT[(tile * 16 + q * 4 + r) * DIM + t * 16 + ln15] = v;
                s_l += v;
                q_l += v * v;
            }
            s_l += __shfl_xor(s_l, 16); s_l += __shfl_xor(s_l, 32);
            q_l += __shfl_xor(q_l, 16); q_l += __shfl_xor(q_l, 32);
            sac[t] += s_l;
            qac[t] += q_l;
        }
    }
    if (lane < 16) {
#pragma unroll
        for (int t = 0; t < 8; t++) {
            atomicAdd(stats + t * 16 + ln15, sac[t]);
            atomicAdd(stats + DIM + t * 16 + ln15, qac[t]);
        }
    }
}

// ---------------- fold BN stats into per-column a,b; reset stats ----------------
__global__ void k_bnfin(float* __restrict__ stats, const float* __restrict__ gamma,
                        const float* __restrict__ beta, float* __restrict__ ab) {
    int c = threadIdx.x;
    float s = stats[c], sq = stats[DIM + c];
    float mean = s * (1.f / N_NODES);
    float var = sq * (1.f / N_NODES) - mean * mean;
    float a = gamma[c] * rsqrtf(var + BN_EPS);
    ab[c] = a;
    ab[DIM + c] = beta[c] - mean * a;
    stats[c] = 0.f;
    stats[DIM + c] = 0.f;
}

// ---------------- h = relu(a*Z+b); Z = h (next-layer base); pool max ----------------
__global__ void k_hnext(float* __restrict__ Z, const float* __restrict__ ab,
                        const int* __restrict__ gids, float* __restrict__ H,
                        unsigned* __restrict__ pool) {
    int t = blockIdx.x * 256 + threadIdx.x;  // N_NODES*32
    int node = t >> 5, c4 = (t & 31) << 2;
    f32x4 v = *(const f32x4*)(Z + node * DIM + c4);
    f32x4 a = *(const f32x4*)(ab + c4);
    f32x4 b = *(const f32x4*)(ab + DIM + c4);
    v.x = fmaxf(a.x * v.x + b.x, 0.f);
    v.y = fmaxf(a.y * v.y + b.y, 0.f);
    v.z = fmaxf(a.z * v.z + b.z, 0.f);
    v.w = fmaxf(a.w * v.w + b.w, 0.f);
    *(f32x4*)(H + node * DIM + c4) = v;
    *(f32x4*)(Z + node * DIM + c4) = v;
    int g = gids[node];
    unsigned* p = pool + g * DIM + c4;
    atomicMax(p + 0, enc_f(v.x));
    atomicMax(p + 1, enc_f(v.y));
    atomicMax(p + 2, enc_f(v.z));
    atomicMax(p + 3, enc_f(v.w));
}

// ---------------- score[g] = sum_l pooled[l][g] @ predW[l] + predb[l] ----------------
__global__ void k_readout(const unsigned* __restrict__ pool, const float* __restrict__ predW,
                          const float* __restrict__ predb, float* __restrict__ out) {
    __shared__ float pl[5][DIM];
    int g = blockIdx.x, c = threadIdx.x;
    for (int l = 0; l < 5; l++) pl[l][c] = dec_f(pool[l * N_GRAPHS * DIM + g * DIM + c]);
    __syncthreads();
    float acc = 0.f;
    for (int l = 0; l < 5; l++) {
        acc += predb[l * DIM + c];
        const float* W = predW + l * DIM * DIM;
#pragma unroll 8
        for (int k = 0; k < DIM; k++) acc += pl[l][k] * W[k * DIM + c];
    }
    out[g * DIM + c] = acc;
}

extern "C" void kernel_launch(void* const* d_in, const int* in_sizes, int n_in,
                              void* d_out, int out_size, void* d_ws, size_t ws_size,
                              hipStream_t stream) {
    const float* h_in = (const float*)d_in[0];
    const int* src = (const int*)d_in[1];
    const int* dst = (const int*)d_in[2];
    const int* gid = (const int*)d_in[3];
    const float* W1s = (const float*)d_in[4];
    const float* W2s = (const float*)d_in[5];
    const float* bn1g = (const float*)d_in[6];
    const float* bn1b = (const float*)d_in[7];
    const float* bn2g = (const float*)d_in[8];
    const float* bn2b = (const float*)d_in[9];
    const float* predW = (const float*)d_in[10];
    const float* predb = (const float*)d_in[11];

    char* ws = (char*)d_ws;
    float* Z = (float*)(ws);                       // 25,600,000 B
    float* Y = (float*)(ws + 25600000);            // 25,600,000 B
    float* H = (float*)(ws + 51200000);            // 25,600,000 B
    short* wt = (short*)(ws + 76800000);           // 8*16384*2 = 262,144 B
    float* stats = (float*)(ws + 77062144);        // 256 floats
    float* ab1 = (float*)(ws + 77063168);          // 256 floats
    float* ab2 = (float*)(ws + 77064192);          // 256 floats
    unsigned* pool = (unsigned*)(ws + 77065216);   // 5*512*128*4 = 1,310,720 B

    k_init<<<1280, 256, 0, stream>>>(pool, stats);
    k_prep_w<<<512, 256, 0, stream>>>(W1s, W2s, wt);
    k_copy_pool<<<6250, 256, 0, stream>>>(h_in, gid, Z, pool);

    for (int l = 0; l < NLAYERS; l++) {
        const float* hp = (l == 0) ? h_in : H;
        k_scatter<<<100000, 256, 0, stream>>>(hp, src, dst, Z);
        k_gemm<false><<<391, 256, 0, stream>>>(Z, wt + l * 16384, ab1, Y, stats);
        k_bnfin<<<1, 128, 0, stream>>>(stats, bn1g + l * DIM, bn1b + l * DIM, ab1);
        k_gemm<true><<<391, 256, 0, stream>>>(Y, wt + (4 + l) * 16384, ab1, Z, stats);
        k_bnfin<<<1, 128, 0, stream>>>(stats, bn2g + l * DIM, bn2b + l * DIM, ab2);
        k_hnext<<<6250, 256, 0, stream>>>(Z, ab2, gid, H, pool + (l + 1) * N_GRAPHS * DIM);
    }
    k_readout<<<512, 128, 0, stream>>>(pool, predW, predb, (float*)d_out);
}

// Round 2
// 1279.112 us; speedup vs baseline: 4.9512x; 4.9512x over previous
//
#include <hip/hip_runtime.h>

#define N_NODES 50000
#define N_EDGES 800000
#define N_GRAPHS 512
#define DIM 128
#define NLAYERS 4
#define BN_EPS 1e-5f
#define NB_SCAN ((N_NODES + 255) / 256)  // 196

typedef float f32x2 __attribute__((ext_vector_type(2)));
typedef float f32x4 __attribute__((ext_vector_type(4)));
typedef short bf16x8 __attribute__((ext_vector_type(8)));

__device__ __forceinline__ short f2bs(float f) {
    union { float f; unsigned u; } v; v.f = f;
    unsigned r = v.u + 0x7FFFu + ((v.u >> 16) & 1u);
    return (short)(r >> 16);
}
__device__ __forceinline__ unsigned enc_f(float f) {
    union { float f; unsigned u; } v; v.f = f;
    return (v.u & 0x80000000u) ? ~v.u : (v.u | 0x80000000u);
}
__device__ __forceinline__ float dec_f(unsigned k) {
    union { unsigned u; float f; } v;
    v.u = (k & 0x80000000u) ? (k ^ 0x80000000u) : ~k;
    return v.f;
}

// ---------------- init: pool keys to enc(-inf); zero stats/deg/cursor ----------------
__global__ void k_init(unsigned* __restrict__ pool, float* __restrict__ stats,
                       int* __restrict__ deg, int* __restrict__ cursor) {
    int i = blockIdx.x * 256 + threadIdx.x;
    if (i < 5 * N_GRAPHS * DIM) pool[i] = 0x007FFFFFu;  // enc(-inf)
    if (i < 256) stats[i] = 0.f;
    if (i < N_NODES) { deg[i] = 0; cursor[i] = 0; }
}

// ---------------- prep: W1s,W2s (fp32 row-major) -> wt[8][n][k] bf16 (W^T) ----------------
__global__ void k_prep_w(const float* __restrict__ W1s, const float* __restrict__ W2s,
                         short* __restrict__ wt) {
    int i = blockIdx.x * 256 + threadIdx.x;  // 8*16384
    int m = i >> 14;
    int r = i & 16383;
    int n = r >> 7, k = r & 127;
    const float* W = (m < 4) ? (W1s + m * 16384) : (W2s + (m - 4) * 16384);
    wt[i] = f2bs(W[k * DIM + n]);
}

// ---------------- CSR build ----------------
__global__ void k_hist(const int* __restrict__ dst, int* __restrict__ deg) {
    int e = blockIdx.x * 256 + threadIdx.x;
    if (e < N_EDGES) atomicAdd(deg + dst[e], 1);
}

__global__ void k_scan1(const int* __restrict__ deg, int* __restrict__ toff,
                        int* __restrict__ bsum) {
    __shared__ int sm[256];
    int t = threadIdx.x, i = blockIdx.x * 256 + t;
    int v = (i < N_NODES) ? deg[i] : 0;
    int x = v;
    sm[t] = x; __syncthreads();
#pragma unroll
    for (int d = 1; d < 256; d <<= 1) {
        int y = (t >= d) ? sm[t - d] : 0;
        __syncthreads();
        sm[t] = x = x + y;
        __syncthreads();
    }
    if (i < N_NODES) toff[i] = x - v;  // exclusive within block
    if (t == 255) bsum[blockIdx.x] = x;
}

__global__ void k_scan2(int* __restrict__ bsum) {
    if (threadIdx.x == 0) {
        int run = 0;
        for (int b = 0; b < NB_SCAN; b++) { int t = bsum[b]; bsum[b] = run; run += t; }
    }
}

__global__ void k_scan3(int* __restrict__ toff, const int* __restrict__ bsum) {
    int i = blockIdx.x * 256 + threadIdx.x;
    if (i < N_NODES) toff[i] += bsum[blockIdx.x];
}

__global__ void k_fill(const int* __restrict__ src, const int* __restrict__ dst,
                       const int* __restrict__ toff, int* __restrict__ cursor,
                       int* __restrict__ eix) {
    int e = blockIdx.x * 256 + threadIdx.x;
    if (e < N_EDGES) {
        int d = dst[e];
        int pos = toff[d] + atomicAdd(cursor + d, 1);
        eix[pos] = src[e];
    }
}

// ---------------- Z[n] = h[n] + sum_{e: dst=n} h[src[e]]  (gather) ----------------
__global__ __launch_bounds__(256) void k_gather(const float* __restrict__ h,
                                                const int* __restrict__ toff,
                                                const int* __restrict__ deg,
                                                const int* __restrict__ eix,
                                                float* __restrict__ Z) {
    int node = blockIdx.x * 4 + (threadIdx.x >> 6);
    int c = (threadIdx.x & 63) * 2;
    int beg = toff[node];
    int end = beg + deg[node];
    f32x2 acc = *(const f32x2*)(h + node * DIM + c);
    int e = beg;
    for (; e + 4 <= end; e += 4) {
        int s0 = eix[e], s1 = eix[e + 1], s2 = eix[e + 2], s3 = eix[e + 3];
        f32x2 v0 = *(const f32x2*)(h + s0 * DIM + c);
        f32x2 v1 = *(const f32x2*)(h + s1 * DIM + c);
        f32x2 v2 = *(const f32x2*)(h + s2 * DIM + c);
        f32x2 v3 = *(const f32x2*)(h + s3 * DIM + c);
        acc += v0 + v1 + v2 + v3;
    }
    for (; e < end; e++) {
        int s0 = eix[e];
        acc += *(const f32x2*)(h + s0 * DIM + c);
    }
    *(f32x2*)(Z + node * DIM + c) = acc;
}

// ---------------- pool[0] max= h ----------------
__global__ void k_pool0(const float* __restrict__ h, const int* __restrict__ gids,
                        unsigned* __restrict__ pool) {
    int t = blockIdx.x * 256 + threadIdx.x;  // N_NODES*32
    int node = t >> 5, c4 = (t & 31) << 2;
    f32x4 v = *(const f32x4*)(h + node * DIM + c4);
    int g = gids[node];
    unsigned* p = pool + g * DIM + c4;
    atomicMax(p + 0, enc_f(v.x));
    atomicMax(p + 1, enc_f(v.y));
    atomicMax(p + 2, enc_f(v.z));
    atomicMax(p + 3, enc_f(v.w));
}

// ---------------- OUT = f(X) @ W  (+ column sum/sumsq stats) ----------------
template <bool XFORM>
__global__ __launch_bounds__(256) void k_gemm(const float* __restrict__ X,
                                              const short* __restrict__ wt,
                                              const float* __restrict__ ab,
                                              float* __restrict__ OUT,
                                              float* __restrict__ stats) {
    const int lane = threadIdx.x & 63;
    const int wid = threadIdx.x >> 6;
    const int ln15 = lane & 15;
    const int q = lane >> 4;  // 0..3

    bf16x8 bfr[8][4];
#pragma unroll
    for (int tl = 0; tl < 8; tl++) {
        int n = tl * 16 + ln15;
#pragma unroll
        for (int s = 0; s < 4; s++)
            bfr[tl][s] = *(const bf16x8*)(wt + n * DIM + s * 32 + q * 8);
    }
    float sac[8], qac[8];
#pragma unroll
    for (int t = 0; t < 8; t++) { sac[t] = 0.f; qac[t] = 0.f; }

    const int wave_global = blockIdx.x * 4 + wid;
    const int nwaves = gridDim.x * 4;
    for (int tile = wave_global; tile < N_NODES / 16; tile += nwaves) {
        const float* xrow = X + (tile * 16 + ln15) * DIM;
        f32x4 acc[8];
#pragma unroll
        for (int t = 0; t < 8; t++) acc[t] = (f32x4){0.f, 0.f, 0.f, 0.f};
#pragma unroll
        for (int s = 0; s < 4; s++) {
            int k0 = s * 32 + q * 8;
            f32x4 x0 = *(const f32x4*)(xrow + k0);
            f32x4 x1 = *(const f32x4*)(xrow + k0 + 4);
            if (XFORM) {
                f32x4 a0 = *(const f32x4*)(ab + k0);
                f32x4 a1 = *(const f32x4*)(ab + k0 + 4);
                f32x4 b0 = *(const f32x4*)(ab + DIM + k0);
                f32x4 b1 = *(const f32x4*)(ab + DIM + k0 + 4);
                x0.x = fmaxf(a0.x * x0.x + b0.x, 0.f);
                x0.y = fmaxf(a0.y * x0.y + b0.y, 0.f);
                x0.z = fmaxf(a0.z * x0.z + b0.z, 0.f);
                x0.w = fmaxf(a0.w * x0.w + b0.w, 0.f);
                x1.x = fmaxf(a1.x * x1.x + b1.x, 0.f);
                x1.y = fmaxf(a1.y * x1.y + b1.y, 0.f);
                x1.z = fmaxf(a1.z * x1.z + b1.z, 0.f);
                x1.w = fmaxf(a1.w * x1.w + b1.w, 0.f);
            }
            bf16x8 afr;
            afr[0] = f2bs(x0.x); afr[1] = f2bs(x0.y);
            afr[2] = f2bs(x0.z); afr[3] = f2bs(x0.w);
            afr[4] = f2bs(x1.x); afr[5] = f2bs(x1.y);
            afr[6] = f2bs(x1.z); afr[7] = f2bs(x1.w);
#pragma unroll
            for (int t = 0; t < 8; t++)
                acc[t] = __builtin_amdgcn_mfma_f32_16x16x32_bf16(afr, bfr[t][s], acc[t], 0, 0, 0);
        }
#pragma unroll
        for (int t = 0; t < 8; t++) {
            float s_l = 0.f, q_l = 0.f;
#pragma unroll
            for (int r = 0; r < 4; r++) {
                float v = acc[t][r];
                OUT[(tile * 16 + q * 4 + r) * DIM + t * 16 + ln15] = v;
                s_l += v;
                q_l += v * v;
            }
            s_l += __shfl_xor(s_l, 16); s_l += __shfl_xor(s_l, 32);
            q_l += __shfl_xor(q_l, 16); q_l += __shfl_xor(q_l, 32);
            sac[t] += s_l;
            qac[t] += q_l;
        }
    }
    if (lane < 16) {
#pragma unroll
        for (int t = 0; t < 8; t++) {
            atomicAdd(stats + t * 16 + ln15, sac[t]);
            atomicAdd(stats + DIM + t * 16 + ln15, qac[t]);
        }
    }
}

// ---------------- fold BN stats into per-column a,b; reset stats ----------------
__global__ void k_bnfin(float* __restrict__ stats, const float* __restrict__ gamma,
                        const float* __restrict__ beta, float* __restrict__ ab) {
    int c = threadIdx.x;
    float s = stats[c], sq = stats[DIM + c];
    float mean = s * (1.f / N_NODES);
    float var = sq * (1.f / N_NODES) - mean * mean;
    float a = gamma[c] * rsqrtf(var + BN_EPS);
    ab[c] = a;
    ab[DIM + c] = beta[c] - mean * a;
    stats[c] = 0.f;
    stats[DIM + c] = 0.f;
}

// ---------------- H = relu(a*Z+b); pool max ----------------
__global__ void k_hnext(const float* __restrict__ Z, const float* __restrict__ ab,
                        const int* __restrict__ gids, float* __restrict__ H,
                        unsigned* __restrict__ pool) {
    int t = blockIdx.x * 256 + threadIdx.x;  // N_NODES*32
    int node = t >> 5, c4 = (t & 31) << 2;
    f32x4 v = *(const f32x4*)(Z + node * DIM + c4);
    f32x4 a = *(const f32x4*)(ab + c4);
    f32x4 b = *(const f32x4*)(ab + DIM + c4);
    v.x = fmaxf(a.x * v.x + b.x, 0.f);
    v.y = fmaxf(a.y * v.y + b.y, 0.f);
    v.z = fmaxf(a.z * v.z + b.z, 0.f);
    v.w = fmaxf(a.w * v.w + b.w, 0.f);
    *(f32x4*)(H + node * DIM + c4) = v;
    int g = gids[node];
    unsigned* p = pool + g * DIM + c4;
    atomicMax(p + 0, enc_f(v.x));
    atomicMax(p + 1, enc_f(v.y));
    atomicMax(p + 2, enc_f(v.z));
    atomicMax(p + 3, enc_f(v.w));
}

// ---------------- score[g] = sum_l pooled[l][g] @ predW[l] + predb[l] ----------------
__global__ void k_readout(const unsigned* __restrict__ pool, const float* __restrict__ predW,
                          const float* __restrict__ predb, float* __restrict__ out) {
    __shared__ float pl[5][DIM];
    int g = blockIdx.x, c = threadIdx.x;
    for (int l = 0; l < 5; l++) pl[l][c] = dec_f(pool[l * N_GRAPHS * DIM + g * DIM + c]);
    __syncthreads();
    float acc = 0.f;
    for (int l = 0; l < 5; l++) {
        acc += predb[l * DIM + c];
        const float* W = predW + l * DIM * DIM;
#pragma unroll 8
        for (int k = 0; k < DIM; k++) acc += pl[l][k] * W[k * DIM + c];
    }
    out[g * DIM + c] = acc;
}

extern "C" void kernel_launch(void* const* d_in, const int* in_sizes, int n_in,
                              void* d_out, int out_size, void* d_ws, size_t ws_size,
                              hipStream_t stream) {
    const float* h_in = (const float*)d_in[0];
    const int* src = (const int*)d_in[1];
    const int* dst = (const int*)d_in[2];
    const int* gid = (const int*)d_in[3];
    const float* W1s = (const float*)d_in[4];
    const float* W2s = (const float*)d_in[5];
    const float* bn1g = (const float*)d_in[6];
    const float* bn1b = (const float*)d_in[7];
    const float* bn2g = (const float*)d_in[8];
    const float* bn2b = (const float*)d_in[9];
    const float* predW = (const float*)d_in[10];
    const float* predb = (const float*)d_in[11];

    char* ws = (char*)d_ws;
    float* Z = (float*)(ws);                        // 25,600,000
    float* Y = (float*)(ws + 25600000);             // 25,600,000
    float* H = (float*)(ws + 51200000);             // 25,600,000
    short* wt = (short*)(ws + 76800000);            // 262,144
    float* stats = (float*)(ws + 77062144);         // 1024
    float* ab1 = (float*)(ws + 77063168);           // 1024
    float* ab2 = (float*)(ws + 77064192);           // 1024
    unsigned* pool = (unsigned*)(ws + 77065216);    // 1,310,720
    int* deg = (int*)(ws + 78375936);               // 200,000
    int* cursor = (int*)(ws + 78575936);            // 200,000
    int* toff = (int*)(ws + 78775936);              // 200,192
    int* bsum = (int*)(ws + 78976128);              // 1,024
    int* eix = (int*)(ws + 78977152);               // 3,200,000  (end: 82,177,152)

    // --- CSR build (once per call) ---
    k_init<<<1280, 256, 0, stream>>>(pool, stats, deg, cursor);
    k_prep_w<<<512, 256, 0, stream>>>(W1s, W2s, wt);
    k_hist<<<3125, 256, 0, stream>>>(dst, deg);
    k_scan1<<<NB_SCAN, 256, 0, stream>>>(deg, toff, bsum);
    k_scan2<<<1, 64, 0, stream>>>(bsum);
    k_scan3<<<NB_SCAN, 256, 0, stream>>>(toff, bsum);
    k_fill<<<3125, 256, 0, stream>>>(src, dst, toff, cursor, eix);
    k_pool0<<<6250, 256, 0, stream>>>(h_in, gid, pool);

    for (int l = 0; l < NLAYERS; l++) {
        const float* hp = (l == 0) ? h_in : H;
        k_gather<<<12500, 256, 0, stream>>>(hp, toff, deg, eix, Z);
        k_gemm<false><<<391, 256, 0, stream>>>(Z, wt + l * 16384, ab1, Y, stats);
        k_bnfin<<<1, 128, 0, stream>>>(stats, bn1g + l * DIM, bn1b + l * DIM, ab1);
        k_gemm<true><<<391, 256, 0, stream>>>(Y, wt + (4 + l) * 16384, ab1, Z, stats);
        k_bnfin<<<1, 128, 0, stream>>>(stats, bn2g + l * DIM, bn2b + l * DIM, ab2);
        k_hnext<<<6250, 256, 0, stream>>>(Z, ab2, gid, H, pool + (l + 1) * N_GRAPHS * DIM);
    }
    k_readout<<<512, 128, 0, stream>>>(pool, predW, predb, (float*)d_out);
}

// Round 3
// 903.290 us; speedup vs baseline: 7.0112x; 1.4161x over previous
//
#include <hip/hip_runtime.h>

#define N_NODES 50000
#define N_EDGES 800000
#define N_GRAPHS 512
#define DIM 128
#define NLAYERS 4
#define BN_EPS 1e-5f
#define NB_SCAN ((N_NODES + 255) / 256)  // 196

typedef float f32x2 __attribute__((ext_vector_type(2)));
typedef float f32x4 __attribute__((ext_vector_type(4)));
typedef short bf16x8 __attribute__((ext_vector_type(8)));

__device__ __forceinline__ short f2bs(float f) {
    union { float f; unsigned u; } v; v.f = f;
    unsigned r = v.u + 0x7FFFu + ((v.u >> 16) & 1u);
    return (short)(r >> 16);
}

// ---------------- init: zero stats/deg/cursor; ranges to empty ----------------
__global__ void k_init(float* __restrict__ stats, int* __restrict__ deg,
                       int* __restrict__ cursor, int* __restrict__ gs, int* __restrict__ ge) {
    int i = blockIdx.x * 256 + threadIdx.x;
    if (i < 256) stats[i] = 0.f;
    if (i < N_NODES) { deg[i] = 0; cursor[i] = 0; }
    if (i < N_GRAPHS) { gs[i] = 0x7FFFFFFF; ge[i] = 0; }
}

// ---------------- prep: W1s,W2s (fp32 row-major) -> wt[8][n][k] bf16 (W^T) ----------------
__global__ void k_prep_w(const float* __restrict__ W1s, const float* __restrict__ W2s,
                         short* __restrict__ wt) {
    int i = blockIdx.x * 256 + threadIdx.x;  // 8*16384
    int m = i >> 14;
    int r = i & 16383;
    int n = r >> 7, k = r & 127;
    const float* W = (m < 4) ? (W1s + m * 16384) : (W2s + (m - 4) * 16384);
    wt[i] = f2bs(W[k * DIM + n]);
}

// ---------------- per-graph node ranges (graph_id is sorted; boundary stores) ----------------
__global__ void k_ranges(const int* __restrict__ gid, int* __restrict__ gs, int* __restrict__ ge) {
    int i = blockIdx.x * 256 + threadIdx.x;
    if (i < N_NODES) {
        int g = gid[i];
        if (i == 0 || gid[i - 1] != g) gs[g] = i;
        if (i == N_NODES - 1 || gid[i + 1] != g) ge[g] = i + 1;
    }
}

// ---------------- CSR build ----------------
__global__ void k_hist(const int* __restrict__ dst, int* __restrict__ deg) {
    int e = blockIdx.x * 256 + threadIdx.x;
    if (e < N_EDGES) atomicAdd(deg + dst[e], 1);
}

__global__ void k_scan1(const int* __restrict__ deg, int* __restrict__ toff,
                        int* __restrict__ bsum) {
    __shared__ int sm[256];
    int t = threadIdx.x, i = blockIdx.x * 256 + t;
    int v = (i < N_NODES) ? deg[i] : 0;
    int x = v;
    sm[t] = x; __syncthreads();
#pragma unroll
    for (int d = 1; d < 256; d <<= 1) {
        int y = (t >= d) ? sm[t - d] : 0;
        __syncthreads();
        sm[t] = x = x + y;
        __syncthreads();
    }
    if (i < N_NODES) toff[i] = x - v;  // exclusive within block
    if (t == 255) bsum[blockIdx.x] = x;
}

__global__ void k_scan2(int* __restrict__ bsum) {
    __shared__ int sm[256];
    int t = threadIdx.x;
    int v = (t < NB_SCAN) ? bsum[t] : 0;
    int x = v;
    sm[t] = x; __syncthreads();
#pragma unroll
    for (int d = 1; d < 256; d <<= 1) {
        int y = (t >= d) ? sm[t - d] : 0;
        __syncthreads();
        sm[t] = x = x + y;
        __syncthreads();
    }
    if (t < NB_SCAN) bsum[t] = x - v;  // exclusive block offsets
}

__global__ void k_scan3(int* __restrict__ toff, const int* __restrict__ bsum) {
    int i = blockIdx.x * 256 + threadIdx.x;
    if (i < N_NODES) toff[i] += bsum[blockIdx.x];
}

__global__ void k_fill(const int* __restrict__ src, const int* __restrict__ dst,
                       const int* __restrict__ toff, int* __restrict__ cursor,
                       int* __restrict__ eix) {
    int e = blockIdx.x * 256 + threadIdx.x;
    if (e < N_EDGES) {
        int d = dst[e];
        int pos = toff[d] + atomicAdd(cursor + d, 1);
        eix[pos] = src[e];
    }
}

// ---------------- Z[n] = h[n] + sum_{e: dst=n} h[src[e]]  (gather) ----------------
__global__ __launch_bounds__(256) void k_gather(const float* __restrict__ h,
                                                const int* __restrict__ toff,
                                                const int* __restrict__ deg,
                                                const int* __restrict__ eix,
                                                float* __restrict__ Z) {
    int node = blockIdx.x * 4 + (threadIdx.x >> 6);
    int c = (threadIdx.x & 63) * 2;
    int beg = toff[node];
    int end = beg + deg[node];
    f32x2 acc = *(const f32x2*)(h + node * DIM + c);
    int e = beg;
    for (; e + 4 <= end; e += 4) {
        int s0 = eix[e], s1 = eix[e + 1], s2 = eix[e + 2], s3 = eix[e + 3];
        f32x2 v0 = *(const f32x2*)(h + s0 * DIM + c);
        f32x2 v1 = *(const f32x2*)(h + s1 * DIM + c);
        f32x2 v2 = *(const f32x2*)(h + s2 * DIM + c);
        f32x2 v3 = *(const f32x2*)(h + s3 * DIM + c);
        acc += v0 + v1 + v2 + v3;
    }
    for (; e < end; e++) {
        int s0 = eix[e];
        acc += *(const f32x2*)(h + s0 * DIM + c);
    }
    *(f32x2*)(Z + node * DIM + c) = acc;
}

// ---------------- pool[0][g] = colmax over h rows of graph g (no atomics) ----------------
__global__ __launch_bounds__(256) void k_pool0seg(const float* __restrict__ h,
                                                  const int* __restrict__ gs,
                                                  const int* __restrict__ ge,
                                                  float* __restrict__ pool) {
    __shared__ f32x2 sm[256];
    int g = blockIdx.x, t = threadIdx.x;
    int c2 = (t & 63) * 2, ro = t >> 6;
    int beg = gs[g], end = ge[g];
    f32x2 mx = (f32x2){-3.402823e38f, -3.402823e38f};
    for (int r = beg + ro; r < end; r += 4) {
        f32x2 v = *(const f32x2*)(h + r * DIM + c2);
        mx.x = fmaxf(mx.x, v.x);
        mx.y = fmaxf(mx.y, v.y);
    }
    sm[t] = mx;
    __syncthreads();
    if (ro == 0) {
        f32x2 m0 = sm[t], m1 = sm[t + 64], m2 = sm[t + 128], m3 = sm[t + 192];
        m0.x = fmaxf(fmaxf(m0.x, m1.x), fmaxf(m2.x, m3.x));
        m0.y = fmaxf(fmaxf(m0.y, m1.y), fmaxf(m2.y, m3.y));
        *(f32x2*)(pool + g * DIM + c2) = m0;
    }
}

// ---------------- OUT = f(X) @ W  (+ column sum/sumsq stats) ----------------
template <bool XFORM>
__global__ __launch_bounds__(256) void k_gemm(const float* __restrict__ X,
                                              const short* __restrict__ wt,
                                              const float* __restrict__ ab,
                                              float* __restrict__ OUT,
                                              float* __restrict__ stats) {
    const int lane = threadIdx.x & 63;
    const int wid = threadIdx.x >> 6;
    const int ln15 = lane & 15;
    const int q = lane >> 4;  // 0..3

    bf16x8 bfr[8][4];
#pragma unroll
    for (int tl = 0; tl < 8; tl++) {
        int n = tl * 16 + ln15;
#pragma unroll
        for (int s = 0; s < 4; s++)
            bfr[tl][s] = *(const bf16x8*)(wt + n * DIM + s * 32 + q * 8);
    }
    float sac[8], qac[8];
#pragma unroll
    for (int t = 0; t < 8; t++) { sac[t] = 0.f; qac[t] = 0.f; }

    const int wave_global = blockIdx.x * 4 + wid;
    const int nwaves = gridDim.x * 4;
    for (int tile = wave_global; tile < N_NODES / 16; tile += nwaves) {
        const float* xrow = X + (tile * 16 + ln15) * DIM;
        f32x4 acc[8];
#pragma unroll
        for (int t = 0; t < 8; t++) acc[t] = (f32x4){0.f, 0.f, 0.f, 0.f};
#pragma unroll
        for (int s = 0; s < 4; s++) {
            int k0 = s * 32 + q * 8;
            f32x4 x0 = *(const f32x4*)(xrow + k0);
            f32x4 x1 = *(const f32x4*)(xrow + k0 + 4);
            if (XFORM) {
                f32x4 a0 = *(const f32x4*)(ab + k0);
                f32x4 a1 = *(const f32x4*)(ab + k0 + 4);
                f32x4 b0 = *(const f32x4*)(ab + DIM + k0);
                f32x4 b1 = *(const f32x4*)(ab + DIM + k0 + 4);
                x0.x = fmaxf(a0.x * x0.x + b0.x, 0.f);
                x0.y = fmaxf(a0.y * x0.y + b0.y, 0.f);
                x0.z = fmaxf(a0.z * x0.z + b0.z, 0.f);
                x0.w = fmaxf(a0.w * x0.w + b0.w, 0.f);
                x1.x = fmaxf(a1.x * x1.x + b1.x, 0.f);
                x1.y = fmaxf(a1.y * x1.y + b1.y, 0.f);
                x1.z = fmaxf(a1.z * x1.z + b1.z, 0.f);
                x1.w = fmaxf(a1.w * x1.w + b1.w, 0.f);
            }
            bf16x8 afr;
            afr[0] = f2bs(x0.x); afr[1] = f2bs(x0.y);
            afr[2] = f2bs(x0.z); afr[3] = f2bs(x0.w);
            afr[4] = f2bs(x1.x); afr[5] = f2bs(x1.y);
            afr[6] = f2bs(x1.z); afr[7] = f2bs(x1.w);
#pragma unroll
            for (int t = 0; t < 8; t++)
                acc[t] = __builtin_amdgcn_mfma_f32_16x16x32_bf16(afr, bfr[t][s], acc[t], 0, 0, 0);
        }
#pragma unroll
        for (int t = 0; t < 8; t++) {
            float s_l = 0.f, q_l = 0.f;
#pragma unroll
            for (int r = 0; r < 4; r++) {
                float v = acc[t][r];
                OUT[(tile * 16 + q * 4 + r) * DIM + t * 16 + ln15] = v;
                s_l += v;
                q_l += v * v;
            }
            s_l += __shfl_xor(s_l, 16); s_l += __shfl_xor(s_l, 32);
            q_l += __shfl_xor(q_l, 16); q_l += __shfl_xor(q_l, 32);
            sac[t] += s_l;
            qac[t] += q_l;
        }
    }
    if (lane < 16) {
#pragma unroll
        for (int t = 0; t < 8; t++) {
            atomicAdd(stats + t * 16 + ln15, sac[t]);
            atomicAdd(stats + DIM + t * 16 + ln15, qac[t]);
        }
    }
}

// ---------------- fold BN stats into per-column a,b; reset stats ----------------
__global__ void k_bnfin(float* __restrict__ stats, const float* __restrict__ gamma,
                        const float* __restrict__ beta, float* __restrict__ ab) {
    int c = threadIdx.x;
    float s = stats[c], sq = stats[DIM + c];
    float mean = s * (1.f / N_NODES);
    float var = sq * (1.f / N_NODES) - mean * mean;
    float a = gamma[c] * rsqrtf(var + BN_EPS);
    ab[c] = a;
    ab[DIM + c] = beta[c] - mean * a;
    stats[c] = 0.f;
    stats[DIM + c] = 0.f;
}

// ---------------- H = relu(a*Z+b); segmented pool max (one block per graph) ----------------
__global__ __launch_bounds__(256) void k_bnpool(const float* __restrict__ Z,
                                                const float* __restrict__ ab,
                                                const int* __restrict__ gs,
                                                const int* __restrict__ ge,
                                                float* __restrict__ H,
                                                float* __restrict__ pool) {
    __shared__ f32x2 sm[256];
    int g = blockIdx.x, t = threadIdx.x;
    int c2 = (t & 63) * 2, ro = t >> 6;
    int beg = gs[g], end = ge[g];
    f32x2 a = *(const f32x2*)(ab + c2);
    f32x2 b = *(const f32x2*)(ab + DIM + c2);
    f32x2 mx = (f32x2){-3.402823e38f, -3.402823e38f};
    for (int r = beg + ro; r < end; r += 4) {
        f32x2 v = *(const f32x2*)(Z + r * DIM + c2);
        v.x = fmaxf(a.x * v.x + b.x, 0.f);
        v.y = fmaxf(a.y * v.y + b.y, 0.f);
        *(f32x2*)(H + r * DIM + c2) = v;
        mx.x = fmaxf(mx.x, v.x);
        mx.y = fmaxf(mx.y, v.y);
    }
    sm[t] = mx;
    __syncthreads();
    if (ro == 0) {
        f32x2 m0 = sm[t], m1 = sm[t + 64], m2 = sm[t + 128], m3 = sm[t + 192];
        m0.x = fmaxf(fmaxf(m0.x, m1.x), fmaxf(m2.x, m3.x));
        m0.y = fmaxf(fmaxf(m0.y, m1.y), fmaxf(m2.y, m3.y));
        *(f32x2*)(pool + g * DIM + c2) = m0;
    }
}

// ---------------- score[g] = sum_l pooled[l][g] @ predW[l] + predb[l] ----------------
__global__ void k_readout(const float* __restrict__ pool, const float* __restrict__ predW,
                          const float* __restrict__ predb, float* __restrict__ out) {
    __shared__ float pl[5][DIM];
    int g = blockIdx.x, c = threadIdx.x;
    for (int l = 0; l < 5; l++) pl[l][c] = pool[l * N_GRAPHS * DIM + g * DIM + c];
    __syncthreads();
    float acc = 0.f;
    for (int l = 0; l < 5; l++) {
        acc += predb[l * DIM + c];
        const float* W = predW + l * DIM * DIM;
#pragma unroll 8
        for (int k = 0; k < DIM; k++) acc += pl[l][k] * W[k * DIM + c];
    }
    out[g * DIM + c] = acc;
}

extern "C" void kernel_launch(void* const* d_in, const int* in_sizes, int n_in,
                              void* d_out, int out_size, void* d_ws, size_t ws_size,
                              hipStream_t stream) {
    const float* h_in = (const float*)d_in[0];
    const int* src = (const int*)d_in[1];
    const int* dst = (const int*)d_in[2];
    const int* gid = (const int*)d_in[3];
    const float* W1s = (const float*)d_in[4];
    const float* W2s = (const float*)d_in[5];
    const float* bn1g = (const float*)d_in[6];
    const float* bn1b = (const float*)d_in[7];
    const float* bn2g = (const float*)d_in[8];
    const float* bn2b = (const float*)d_in[9];
    const float* predW = (const float*)d_in[10];
    const float* predb = (const float*)d_in[11];

    char* ws = (char*)d_ws;
    float* Z = (float*)(ws);                        // 25,600,000
    float* Y = (float*)(ws + 25600000);             // 25,600,000
    float* H = (float*)(ws + 51200000);             // 25,600,000
    short* wt = (short*)(ws + 76800000);            // 262,144
    float* stats = (float*)(ws + 77062144);         // 1,024
    float* ab1 = (float*)(ws + 77063168);           // 1,024
    float* ab2 = (float*)(ws + 77064192);           // 1,024
    float* pool = (float*)(ws + 77065216);          // 1,310,720
    int* deg = (int*)(ws + 78375936);               // 200,000
    int* cursor = (int*)(ws + 78575936);            // 200,000
    int* toff = (int*)(ws + 78775936);              // 200,192
    int* bsum = (int*)(ws + 78976128);              // 1,024
    int* eix = (int*)(ws + 78977152);               // 3,200,000
    int* gs = (int*)(ws + 82177152);                // 2,048
    int* ge = (int*)(ws + 82179200);                // 2,048  (end: 82,181,248)

    // --- prep (once per call) ---
    k_init<<<NB_SCAN, 256, 0, stream>>>(stats, deg, cursor, gs, ge);
    k_prep_w<<<512, 256, 0, stream>>>(W1s, W2s, wt);
    k_ranges<<<NB_SCAN, 256, 0, stream>>>(gid, gs, ge);
    k_hist<<<3125, 256, 0, stream>>>(dst, deg);
    k_scan1<<<NB_SCAN, 256, 0, stream>>>(deg, toff, bsum);
    k_scan2<<<1, 256, 0, stream>>>(bsum);
    k_scan3<<<NB_SCAN, 256, 0, stream>>>(toff, bsum);
    k_fill<<<3125, 256, 0, stream>>>(src, dst, toff, cursor, eix);
    k_pool0seg<<<N_GRAPHS, 256, 0, stream>>>(h_in, gs, ge, pool);

    for (int l = 0; l < NLAYERS; l++) {
        const float* hp = (l == 0) ? h_in : H;
        k_gather<<<12500, 256, 0, stream>>>(hp, toff, deg, eix, Z);
        k_gemm<false><<<391, 256, 0, stream>>>(Z, wt + l * 16384, ab1, Y, stats);
        k_bnfin<<<1, 128, 0, stream>>>(stats, bn1g + l * DIM, bn1b + l * DIM, ab1);
        k_gemm<true><<<391, 256, 0, stream>>>(Y, wt + (4 + l) * 16384, ab1, Z, stats);
        k_bnfin<<<1, 128, 0, stream>>>(stats, bn2g + l * DIM, bn2b + l * DIM, ab2);
        k_bnpool<<<N_GRAPHS, 256, 0, stream>>>(Z, ab2, gs, ge, H, pool + (l + 1) * N_GRAPHS * DIM);
    }
    k_readout<<<512, 128, 0, stream>>>(pool, predW, predb, (float*)d_out);
}

// Round 4
// 797.643 us; speedup vs baseline: 7.9399x; 1.1324x over previous
//
#include <hip/hip_runtime.h>

#define N_NODES 50000
#define N_EDGES 800000
#define N_GRAPHS 512
#define DIM 128
#define NLAYERS 4
#define BN_EPS 1e-5f
#define NB_SCAN ((N_NODES + 255) / 256)  // 196
#define WPAD 136                          // LDS W row stride (shorts): 272B = 17*16 -> aligned, 2-way banks

typedef unsigned short u16;
typedef float f32x2 __attribute__((ext_vector_type(2)));
typedef float f32x4 __attribute__((ext_vector_type(4)));
typedef short bf16x8 __attribute__((ext_vector_type(8)));

__device__ __forceinline__ short f2bs(float f) {
    union { float f; unsigned u; } v; v.f = f;
    unsigned r = v.u + 0x7FFFu + ((v.u >> 16) & 1u);
    return (short)(r >> 16);
}
__device__ __forceinline__ float bu2f(unsigned u) {
    union { unsigned u; float f; } v; v.u = u << 16;
    return v.f;
}
__device__ __forceinline__ unsigned packbf(float x, float y) {
    return ((unsigned)(u16)f2bs(y) << 16) | (unsigned)(u16)f2bs(x);
}

// ---------------- init: zero stats4/deg/cursor; ranges empty ----------------
__global__ void k_init(float* __restrict__ stats4, int* __restrict__ deg,
                       int* __restrict__ cursor, int* __restrict__ gs, int* __restrict__ ge) {
    int i = blockIdx.x * 256 + threadIdx.x;
    if (i < 1024) stats4[i] = 0.f;
    if (i < N_NODES) { deg[i] = 0; cursor[i] = 0; }
    if (i < N_GRAPHS) { gs[i] = 0x7FFFFFFF; ge[i] = 0; }
}

// ---------------- prep: W1s,W2s (fp32 row-major) -> wt[8][n][k] bf16 (W^T) ----------------
__global__ void k_prep_w(const float* __restrict__ W1s, const float* __restrict__ W2s,
                         short* __restrict__ wt) {
    int i = blockIdx.x * 256 + threadIdx.x;  // 8*16384
    int m = i >> 14;
    int r = i & 16383;
    int n = r >> 7, k = r & 127;
    const float* W = (m < 4) ? (W1s + m * 16384) : (W2s + (m - 4) * 16384);
    wt[i] = f2bs(W[k * DIM + n]);
}

// ---------------- prep: h_in fp32 -> hb bf16 (packed pairs) ----------------
__global__ void k_prep_h(const float* __restrict__ h, unsigned* __restrict__ hb) {
    int i = blockIdx.x * 256 + threadIdx.x;  // 3.2M
    f32x2 v = *(const f32x2*)(h + i * 2);
    hb[i] = packbf(v.x, v.y);
}

// ---------------- per-graph node ranges (graph_id sorted) ----------------
__global__ void k_ranges(const int* __restrict__ gid, int* __restrict__ gs, int* __restrict__ ge) {
    int i = blockIdx.x * 256 + threadIdx.x;
    if (i < N_NODES) {
        int g = gid[i];
        if (i == 0 || gid[i - 1] != g) gs[g] = i;
        if (i == N_NODES - 1 || gid[i + 1] != g) ge[g] = i + 1;
    }
}

// ---------------- CSR build ----------------
__global__ void k_hist(const int* __restrict__ dst, int* __restrict__ deg) {
    int e = blockIdx.x * 256 + threadIdx.x;
    if (e < N_EDGES) atomicAdd(deg + dst[e], 1);
}

__global__ void k_scan1(const int* __restrict__ deg, int* __restrict__ toff,
                        int* __restrict__ bsum) {
    __shared__ int sm[256];
    int t = threadIdx.x, i = blockIdx.x * 256 + t;
    int v = (i < N_NODES) ? deg[i] : 0;
    int x = v;
    sm[t] = x; __syncthreads();
#pragma unroll
    for (int d = 1; d < 256; d <<= 1) {
        int y = (t >= d) ? sm[t - d] : 0;
        __syncthreads();
        sm[t] = x = x + y;
        __syncthreads();
    }
    if (i < N_NODES) toff[i] = x - v;
    if (t == 255) bsum[blockIdx.x] = x;
}

__global__ void k_scan2(int* __restrict__ bsum) {
    __shared__ int sm[256];
    int t = threadIdx.x;
    int v = (t < NB_SCAN) ? bsum[t] : 0;
    int x = v;
    sm[t] = x; __syncthreads();
#pragma unroll
    for (int d = 1; d < 256; d <<= 1) {
        int y = (t >= d) ? sm[t - d] : 0;
        __syncthreads();
        sm[t] = x = x + y;
        __syncthreads();
    }
    if (t < NB_SCAN) bsum[t] = x - v;
}

__global__ void k_scan3(int* __restrict__ toff, const int* __restrict__ bsum) {
    int i = blockIdx.x * 256 + threadIdx.x;
    if (i < N_NODES) toff[i] += bsum[blockIdx.x];
}

__global__ void k_fill(const int* __restrict__ src, const int* __restrict__ dst,
                       const int* __restrict__ toff, int* __restrict__ cursor,
                       int* __restrict__ eix) {
    int e = blockIdx.x * 256 + threadIdx.x;
    if (e < N_EDGES) {
        int d = dst[e];
        int pos = toff[d] + atomicAdd(cursor + d, 1);
        eix[pos] = src[e];
    }
}

// ---------------- Z[n] = h[n] + sum h[src]  (bf16 in/out, fp32 accum) ----------------
__global__ __launch_bounds__(256) void k_gather(const unsigned* __restrict__ hp,
                                                const int* __restrict__ toff,
                                                const int* __restrict__ deg,
                                                const int* __restrict__ eix,
                                                unsigned* __restrict__ Z) {
    int node = blockIdx.x * 4 + (threadIdx.x >> 6);
    int lane = threadIdx.x & 63;
    unsigned w = hp[node * 64 + lane];
    float ax = bu2f(w & 0xffffu), ay = bu2f(w >> 16);
    int beg = toff[node], end = beg + deg[node];
    int e = beg;
    for (; e + 8 <= end; e += 8) {
        int s0 = eix[e], s1 = eix[e + 1], s2 = eix[e + 2], s3 = eix[e + 3];
        int s4 = eix[e + 4], s5 = eix[e + 5], s6 = eix[e + 6], s7 = eix[e + 7];
        unsigned w0 = hp[s0 * 64 + lane], w1 = hp[s1 * 64 + lane];
        unsigned w2 = hp[s2 * 64 + lane], w3 = hp[s3 * 64 + lane];
        unsigned w4 = hp[s4 * 64 + lane], w5 = hp[s5 * 64 + lane];
        unsigned w6 = hp[s6 * 64 + lane], w7 = hp[s7 * 64 + lane];
        float x01 = bu2f(w0 & 0xffffu) + bu2f(w1 & 0xffffu);
        float x23 = bu2f(w2 & 0xffffu) + bu2f(w3 & 0xffffu);
        float x45 = bu2f(w4 & 0xffffu) + bu2f(w5 & 0xffffu);
        float x67 = bu2f(w6 & 0xffffu) + bu2f(w7 & 0xffffu);
        float y01 = bu2f(w0 >> 16) + bu2f(w1 >> 16);
        float y23 = bu2f(w2 >> 16) + bu2f(w3 >> 16);
        float y45 = bu2f(w4 >> 16) + bu2f(w5 >> 16);
        float y67 = bu2f(w6 >> 16) + bu2f(w7 >> 16);
        ax += (x01 + x23) + (x45 + x67);
        ay += (y01 + y23) + (y45 + y67);
    }
    for (; e < end; e++) {
        int s = eix[e];
        unsigned ww = hp[s * 64 + lane];
        ax += bu2f(ww & 0xffffu);
        ay += bu2f(ww >> 16);
    }
    Z[node * 64 + lane] = packbf(ax, ay);
}

// ---------------- pool[0][g] = colmax over fp32 h rows of graph g ----------------
__global__ __launch_bounds__(256) void k_pool0seg(const float* __restrict__ h,
                                                  const int* __restrict__ gs,
                                                  const int* __restrict__ ge,
                                                  float* __restrict__ pool) {
    __shared__ f32x2 sm[256];
    int g = blockIdx.x, t = threadIdx.x;
    int c2 = (t & 63) * 2, ro = t >> 6;
    int beg = gs[g], end = ge[g];
    f32x2 mx = (f32x2){-3.402823e38f, -3.402823e38f};
    for (int r = beg + ro; r < end; r += 4) {
        f32x2 v = *(const f32x2*)(h + r * DIM + c2);
        mx.x = fmaxf(mx.x, v.x);
        mx.y = fmaxf(mx.y, v.y);
    }
    sm[t] = mx;
    __syncthreads();
    if (ro == 0) {
        f32x2 m0 = sm[t], m1 = sm[t + 64], m2 = sm[t + 128], m3 = sm[t + 192];
        m0.x = fmaxf(fmaxf(m0.x, m1.x), fmaxf(m2.x, m3.x));
        m0.y = fmaxf(fmaxf(m0.y, m1.y), fmaxf(m2.y, m3.y));
        *(f32x2*)(pool + g * DIM + c2) = m0;
    }
}

// ---------------- GEMM: OUT = f(X) @ W, W in LDS, stats via LDS+replicated atomics ----
// XFORM=0: X bf16 -> OUT fp32 (Y).  XFORM=1: X fp32, f=relu(a*x+b) -> OUT bf16 (Zraw).
template <bool XFORM>
__global__ __launch_bounds__(256, 4) void k_gemm(const void* __restrict__ Xv,
                                                 const short* __restrict__ wt,
                                                 const float* __restrict__ ab,
                                                 void* __restrict__ OUTv,
                                                 float* __restrict__ stats4) {
    __shared__ short wsh[128 * WPAD];
    __shared__ float smst[256];
    const int tid = threadIdx.x;
    {   // stage W: 32KB, each thread copies half a row (128B) with row padding
        int n = tid >> 1, hh = tid & 1;
        const int4* g = (const int4*)(wt + n * 128 + hh * 64);
        int4* l = (int4*)(wsh + n * WPAD + hh * 64);
#pragma unroll
        for (int i = 0; i < 8; i++) l[i] = g[i];
    }
    smst[tid] = 0.f;
    __syncthreads();

    const int lane = tid & 63, wid = tid >> 6;
    const int ln15 = lane & 15, q = lane >> 4;

    float sac[8], qac[8];
#pragma unroll
    for (int t = 0; t < 8; t++) { sac[t] = 0.f; qac[t] = 0.f; }

    f32x4 aA[4], aB[4], bA[4], bB[4];
    if (XFORM) {
#pragma unroll
        for (int s = 0; s < 4; s++) {
            int k0 = s * 32 + q * 8;
            aA[s] = *(const f32x4*)(ab + k0);
            aB[s] = *(const f32x4*)(ab + k0 + 4);
            bA[s] = *(const f32x4*)(ab + DIM + k0);
            bB[s] = *(const f32x4*)(ab + DIM + k0 + 4);
        }
    }

    for (int tile = blockIdx.x * 4 + wid; tile < N_NODES / 16; tile += gridDim.x * 4) {
        bf16x8 afr[4];
        if constexpr (!XFORM) {
            const u16* xr = (const u16*)Xv + (tile * 16 + ln15) * DIM;
#pragma unroll
            for (int s = 0; s < 4; s++)
                afr[s] = *(const bf16x8*)(xr + s * 32 + q * 8);
        } else {
            const float* xr = (const float*)Xv + (tile * 16 + ln15) * DIM;
#pragma unroll
            for (int s = 0; s < 4; s++) {
                int k0 = s * 32 + q * 8;
                f32x4 x0 = *(const f32x4*)(xr + k0);
                f32x4 x1 = *(const f32x4*)(xr + k0 + 4);
                x0.x = fmaxf(aA[s].x * x0.x + bA[s].x, 0.f);
                x0.y = fmaxf(aA[s].y * x0.y + bA[s].y, 0.f);
                x0.z = fmaxf(aA[s].z * x0.z + bA[s].z, 0.f);
                x0.w = fmaxf(aA[s].w * x0.w + bA[s].w, 0.f);
                x1.x = fmaxf(aB[s].x * x1.x + bB[s].x, 0.f);
                x1.y = fmaxf(aB[s].y * x1.y + bB[s].y, 0.f);
                x1.z = fmaxf(aB[s].z * x1.z + bB[s].z, 0.f);
                x1.w = fmaxf(aB[s].w * x1.w + bB[s].w, 0.f);
                bf16x8 a;
                a[0] = f2bs(x0.x); a[1] = f2bs(x0.y); a[2] = f2bs(x0.z); a[3] = f2bs(x0.w);
                a[4] = f2bs(x1.x); a[5] = f2bs(x1.y); a[6] = f2bs(x1.z); a[7] = f2bs(x1.w);
                afr[s] = a;
            }
        }
        f32x4 acc[8];
#pragma unroll
        for (int t = 0; t < 8; t++) acc[t] = (f32x4){0.f, 0.f, 0.f, 0.f};
#pragma unroll
        for (int s = 0; s < 4; s++) {
#pragma unroll
            for (int t = 0; t < 8; t++) {
                bf16x8 bfr = *(const bf16x8*)(wsh + (t * 16 + ln15) * WPAD + s * 32 + q * 8);
                acc[t] = __builtin_amdgcn_mfma_f32_16x16x32_bf16(afr[s], bfr, acc[t], 0, 0, 0);
            }
        }
#pragma unroll
        for (int t = 0; t < 8; t++) {
            float s_l = 0.f, q_l = 0.f;
#pragma unroll
            for (int r = 0; r < 4; r++) {
                float v = acc[t][r];
                int idx = (tile * 16 + q * 4 + r) * DIM + t * 16 + ln15;
                if constexpr (!XFORM) ((float*)OUTv)[idx] = v;
                else ((u16*)OUTv)[idx] = (u16)f2bs(v);
                s_l += v;
                q_l += v * v;
            }
            s_l += __shfl_xor(s_l, 16); s_l += __shfl_xor(s_l, 32);
            q_l += __shfl_xor(q_l, 16); q_l += __shfl_xor(q_l, 32);
            sac[t] += s_l;
            qac[t] += q_l;
        }
    }
    if (lane < 16) {
#pragma unroll
        for (int t = 0; t < 8; t++) {
            atomicAdd(&smst[t * 16 + ln15], sac[t]);
            atomicAdd(&smst[128 + t * 16 + ln15], qac[t]);
        }
    }
    __syncthreads();
    atomicAdd(stats4 + (blockIdx.x & 3) * 256 + tid, smst[tid]);
}

// ---------------- fold BN stats (4 replicas) into a,b; reset ----------------
__global__ void k_bnfin(float* __restrict__ stats4, const float* __restrict__ gamma,
                        const float* __restrict__ beta, float* __restrict__ ab) {
    int c = threadIdx.x;  // 128
    float s = 0.f, sq = 0.f;
#pragma unroll
    for (int j = 0; j < 4; j++) {
        s += stats4[j * 256 + c];
        sq += stats4[j * 256 + 128 + c];
        stats4[j * 256 + c] = 0.f;
        stats4[j * 256 + 128 + c] = 0.f;
    }
    float mean = s * (1.f / N_NODES);
    float var = sq * (1.f / N_NODES) - mean * mean;
    float a = gamma[c] * rsqrtf(var + BN_EPS);
    ab[c] = a;
    ab[DIM + c] = beta[c] - mean * a;
}

// ---------------- H = relu(a*Zraw+b) (bf16), segmented pool (fp32) ----------------
__global__ __launch_bounds__(256) void k_bnpool(const unsigned* __restrict__ Zb,
                                                const float* __restrict__ ab,
                                                const int* __restrict__ gs,
                                                const int* __restrict__ ge,
                                                unsigned* __restrict__ H,
                                                float* __restrict__ pool) {
    __shared__ f32x2 sm[256];
    int g = blockIdx.x, t = threadIdx.x;
    int ci = t & 63, ro = t >> 6;
    int beg = gs[g], end = ge[g];
    f32x2 a = *(const f32x2*)(ab + ci * 2);
    f32x2 b = *(const f32x2*)(ab + DIM + ci * 2);
    f32x2 mx = (f32x2){-3.402823e38f, -3.402823e38f};
    for (int r = beg + ro; r < end; r += 4) {
        unsigned w = Zb[r * 64 + ci];
        float vx = fmaxf(a.x * bu2f(w & 0xffffu) + b.x, 0.f);
        float vy = fmaxf(a.y * bu2f(w >> 16) + b.y, 0.f);
        H[r * 64 + ci] = packbf(vx, vy);
        mx.x = fmaxf(mx.x, vx);
        mx.y = fmaxf(mx.y, vy);
    }
    sm[t] = mx;
    __syncthreads();
    if (ro == 0) {
        f32x2 m0 = sm[t], m1 = sm[t + 64], m2 = sm[t + 128], m3 = sm[t + 192];
        m0.x = fmaxf(fmaxf(m0.x, m1.x), fmaxf(m2.x, m3.x));
        m0.y = fmaxf(fmaxf(m0.y, m1.y), fmaxf(m2.y, m3.y));
        *(f32x2*)(pool + g * DIM + ci * 2) = m0;
    }
}

// ---------------- score[g] = sum_l pooled[l][g] @ predW[l] + predb[l] ----------------
__global__ void k_readout(const float* __restrict__ pool, const float* __restrict__ predW,
                          const float* __restrict__ predb, float* __restrict__ out) {
    __shared__ float pl[5][DIM];
    int g = blockIdx.x, c = threadIdx.x;
    for (int l = 0; l < 5; l++) pl[l][c] = pool[l * N_GRAPHS * DIM + g * DIM + c];
    __syncthreads();
    float acc = 0.f;
    for (int l = 0; l < 5; l++) {
        acc += predb[l * DIM + c];
        const float* W = predW + l * DIM * DIM;
#pragma unroll 8
        for (int k = 0; k < DIM; k++) acc += pl[l][k] * W[k * DIM + c];
    }
    out[g * DIM + c] = acc;
}

extern "C" void kernel_launch(void* const* d_in, const int* in_sizes, int n_in,
                              void* d_out, int out_size, void* d_ws, size_t ws_size,
                              hipStream_t stream) {
    const float* h_in = (const float*)d_in[0];
    const int* src = (const int*)d_in[1];
    const int* dst = (const int*)d_in[2];
    const int* gid = (const int*)d_in[3];
    const float* W1s = (const float*)d_in[4];
    const float* W2s = (const float*)d_in[5];
    const float* bn1g = (const float*)d_in[6];
    const float* bn1b = (const float*)d_in[7];
    const float* bn2g = (const float*)d_in[8];
    const float* bn2b = (const float*)d_in[9];
    const float* predW = (const float*)d_in[10];
    const float* predb = (const float*)d_in[11];

    char* ws = (char*)d_ws;
    unsigned* hb = (unsigned*)(ws);                 // 12,800,000
    unsigned* Zb = (unsigned*)(ws + 12800000);      // 12,800,000 (bf16 Z / Zraw)
    float* Y = (float*)(ws + 25600000);             // 25,600,000
    unsigned* H = (unsigned*)(ws + 51200000);       // 12,800,000 (bf16)
    short* wt = (short*)(ws + 64000000);            // 262,144
    float* stats4 = (float*)(ws + 64262144);        // 4,096
    float* ab1 = (float*)(ws + 64266240);           // 1,024
    float* ab2 = (float*)(ws + 64267264);           // 1,024
    float* pool = (float*)(ws + 64268288);          // 1,310,720
    int* deg = (int*)(ws + 65579008);               // 200,000
    int* cursor = (int*)(ws + 65779008);            // 200,000
    int* toff = (int*)(ws + 65979008);              // 200,192
    int* bsum = (int*)(ws + 66179200);              // 1,024
    int* eix = (int*)(ws + 66180224);               // 3,200,000
    int* gs = (int*)(ws + 69380224);                // 2,048
    int* ge = (int*)(ws + 69382272);                // 2,048   (end: 69,384,320)

    k_init<<<NB_SCAN, 256, 0, stream>>>(stats4, deg, cursor, gs, ge);
    k_prep_w<<<512, 256, 0, stream>>>(W1s, W2s, wt);
    k_prep_h<<<12500, 256, 0, stream>>>(h_in, hb);
    k_ranges<<<NB_SCAN, 256, 0, stream>>>(gid, gs, ge);
    k_hist<<<3125, 256, 0, stream>>>(dst, deg);
    k_scan1<<<NB_SCAN, 256, 0, stream>>>(deg, toff, bsum);
    k_scan2<<<1, 256, 0, stream>>>(bsum);
    k_scan3<<<NB_SCAN, 256, 0, stream>>>(toff, bsum);
    k_fill<<<3125, 256, 0, stream>>>(src, dst, toff, cursor, eix);
    k_pool0seg<<<N_GRAPHS, 256, 0, stream>>>(h_in, gs, ge, pool);

    for (int l = 0; l < NLAYERS; l++) {
        const unsigned* hp = (l == 0) ? hb : H;
        k_gather<<<12500, 256, 0, stream>>>(hp, toff, deg, eix, Zb);
        k_gemm<false><<<512, 256, 0, stream>>>(Zb, wt + l * 16384, ab1, Y, stats4);
        k_bnfin<<<1, 128, 0, stream>>>(stats4, bn1g + l * DIM, bn1b + l * DIM, ab1);
        k_gemm<true><<<512, 256, 0, stream>>>(Y, wt + (4 + l) * 16384, ab1, Zb, stats4);
        k_bnfin<<<1, 128, 0, stream>>>(stats4, bn2g + l * DIM, bn2b + l * DIM, ab2);
        k_bnpool<<<N_GRAPHS, 256, 0, stream>>>(Zb, ab2, gs, ge, H, pool + (l + 1) * N_GRAPHS * DIM);
    }
    k_readout<<<512, 128, 0, stream>>>(pool, predW, predb, (float*)d_out);
}

// Round 5
// 793.924 us; speedup vs baseline: 7.9771x; 1.0047x over previous
//
#include <hip/hip_runtime.h>

#define N_NODES 50000
#define N_EDGES 800000
#define N_GRAPHS 512
#define DIM 128
#define NLAYERS 4
#define BN_EPS 1e-5f
#define NB_SCAN ((N_NODES + 255) / 256)  // 196
#define WPAD 136  // LDS W row stride (shorts): 272B, 16B-aligned, spreads banks

typedef unsigned short u16;
typedef float f32x2 __attribute__((ext_vector_type(2)));
typedef float f32x4 __attribute__((ext_vector_type(4)));
typedef short bf16x8 __attribute__((ext_vector_type(8)));

__device__ __forceinline__ short f2bs(float f) {
    union { float f; unsigned u; } v; v.f = f;
    unsigned r = v.u + 0x7FFFu + ((v.u >> 16) & 1u);
    return (short)(r >> 16);
}
__device__ __forceinline__ float bu2f(unsigned u) {
    union { unsigned u; float f; } v; v.u = u << 16;
    return v.f;
}
__device__ __forceinline__ unsigned packbf(float x, float y) {
    return ((unsigned)(u16)f2bs(y) << 16) | (unsigned)(u16)f2bs(x);
}

// ---------------- init ----------------
__global__ void k_init(float* __restrict__ stats8, int* __restrict__ deg,
                       int* __restrict__ cursor, int* __restrict__ gs, int* __restrict__ ge) {
    int i = blockIdx.x * 256 + threadIdx.x;
    if (i < 2048) stats8[i] = 0.f;
    if (i < N_NODES) { deg[i] = 0; cursor[i] = 0; }
    if (i < N_GRAPHS) { gs[i] = 0x7FFFFFFF; ge[i] = 0; }
}

// ---------------- prep: W -> W^T bf16 ----------------
__global__ void k_prep_w(const float* __restrict__ W1s, const float* __restrict__ W2s,
                         short* __restrict__ wt) {
    int i = blockIdx.x * 256 + threadIdx.x;  // 8*16384
    int m = i >> 14;
    int r = i & 16383;
    int n = r >> 7, k = r & 127;
    const float* W = (m < 4) ? (W1s + m * 16384) : (W2s + (m - 4) * 16384);
    wt[i] = f2bs(W[k * DIM + n]);
}

// ---------------- prep: h fp32 -> bf16 packed ----------------
__global__ void k_prep_h(const float* __restrict__ h, unsigned* __restrict__ hb) {
    int i = blockIdx.x * 256 + threadIdx.x;  // 3.2M
    f32x2 v = *(const f32x2*)(h + i * 2);
    hb[i] = packbf(v.x, v.y);
}

// ---------------- per-graph ranges (sorted gid) ----------------
__global__ void k_ranges(const int* __restrict__ gid, int* __restrict__ gs, int* __restrict__ ge) {
    int i = blockIdx.x * 256 + threadIdx.x;
    if (i < N_NODES) {
        int g = gid[i];
        if (i == 0 || gid[i - 1] != g) gs[g] = i;
        if (i == N_NODES - 1 || gid[i + 1] != g) ge[g] = i + 1;
    }
}

// ---------------- CSR build ----------------
__global__ void k_hist(const int* __restrict__ dst, int* __restrict__ deg) {
    int e = blockIdx.x * 256 + threadIdx.x;
    if (e < N_EDGES) atomicAdd(deg + dst[e], 1);
}

__global__ void k_scan1(const int* __restrict__ deg, int* __restrict__ toff,
                        int* __restrict__ bsum) {
    __shared__ int sm[256];
    int t = threadIdx.x, i = blockIdx.x * 256 + t;
    int v = (i < N_NODES) ? deg[i] : 0;
    int x = v;
    sm[t] = x; __syncthreads();
#pragma unroll
    for (int d = 1; d < 256; d <<= 1) {
        int y = (t >= d) ? sm[t - d] : 0;
        __syncthreads();
        sm[t] = x = x + y;
        __syncthreads();
    }
    if (i < N_NODES) toff[i] = x - v;
    if (t == 255) bsum[blockIdx.x] = x;
}

__global__ void k_scan2(int* __restrict__ bsum) {
    __shared__ int sm[256];
    int t = threadIdx.x;
    int v = (t < NB_SCAN) ? bsum[t] : 0;
    int x = v;
    sm[t] = x; __syncthreads();
#pragma unroll
    for (int d = 1; d < 256; d <<= 1) {
        int y = (t >= d) ? sm[t - d] : 0;
        __syncthreads();
        sm[t] = x = x + y;
        __syncthreads();
    }
    if (t < NB_SCAN) bsum[t] = x - v;
}

__global__ void k_scan3(int* __restrict__ toff, const int* __restrict__ bsum) {
    int i = blockIdx.x * 256 + threadIdx.x;
    if (i < N_NODES) toff[i] += bsum[blockIdx.x];
}

__global__ void k_fill(const int* __restrict__ src, const int* __restrict__ dst,
                       const int* __restrict__ toff, int* __restrict__ cursor,
                       int* __restrict__ eix) {
    int e = blockIdx.x * 256 + threadIdx.x;
    if (e < N_EDGES) {
        int d = dst[e];
        int pos = toff[d] + atomicAdd(cursor + d, 1);
        eix[pos] = src[e];
    }
}

// ---------------- Z[n] = h[n] + sum h[src]  (bf16, fp32 accum) ----------------
__global__ __launch_bounds__(256) void k_gather(const unsigned* __restrict__ hp,
                                                const int* __restrict__ toff,
                                                const int* __restrict__ deg,
                                                const int* __restrict__ eix,
                                                unsigned* __restrict__ Z) {
    int node = blockIdx.x * 4 + (threadIdx.x >> 6);
    int lane = threadIdx.x & 63;
    unsigned w = hp[node * 64 + lane];
    float ax = bu2f(w & 0xffffu), ay = bu2f(w >> 16);
    int beg = toff[node], end = beg + deg[node];
    int e = beg;
    for (; e + 8 <= end; e += 8) {
        int s0 = eix[e], s1 = eix[e + 1], s2 = eix[e + 2], s3 = eix[e + 3];
        int s4 = eix[e + 4], s5 = eix[e + 5], s6 = eix[e + 6], s7 = eix[e + 7];
        unsigned w0 = hp[s0 * 64 + lane], w1 = hp[s1 * 64 + lane];
        unsigned w2 = hp[s2 * 64 + lane], w3 = hp[s3 * 64 + lane];
        unsigned w4 = hp[s4 * 64 + lane], w5 = hp[s5 * 64 + lane];
        unsigned w6 = hp[s6 * 64 + lane], w7 = hp[s7 * 64 + lane];
        float x01 = bu2f(w0 & 0xffffu) + bu2f(w1 & 0xffffu);
        float x23 = bu2f(w2 & 0xffffu) + bu2f(w3 & 0xffffu);
        float x45 = bu2f(w4 & 0xffffu) + bu2f(w5 & 0xffffu);
        float x67 = bu2f(w6 & 0xffffu) + bu2f(w7 & 0xffffu);
        float y01 = bu2f(w0 >> 16) + bu2f(w1 >> 16);
        float y23 = bu2f(w2 >> 16) + bu2f(w3 >> 16);
        float y45 = bu2f(w4 >> 16) + bu2f(w5 >> 16);
        float y67 = bu2f(w6 >> 16) + bu2f(w7 >> 16);
        ax += (x01 + x23) + (x45 + x67);
        ay += (y01 + y23) + (y45 + y67);
    }
    for (; e < end; e++) {
        int s = eix[e];
        unsigned ww = hp[s * 64 + lane];
        ax += bu2f(ww & 0xffffu);
        ay += bu2f(ww >> 16);
    }
    Z[node * 64 + lane] = packbf(ax, ay);
}

// ---------------- pool[0][g] = colmax over fp32 h rows of graph g ----------------
__global__ __launch_bounds__(256) void k_pool0seg(const float* __restrict__ h,
                                                  const int* __restrict__ gs,
                                                  const int* __restrict__ ge,
                                                  float* __restrict__ pool) {
    __shared__ f32x2 sm[256];
    int g = blockIdx.x, t = threadIdx.x;
    int c2 = (t & 63) * 2, ro = t >> 6;
    int beg = gs[g], end = ge[g];
    f32x2 mx = (f32x2){-3.402823e38f, -3.402823e38f};
    for (int r = beg + ro; r < end; r += 4) {
        f32x2 v = *(const f32x2*)(h + r * DIM + c2);
        mx.x = fmaxf(mx.x, v.x);
        mx.y = fmaxf(mx.y, v.y);
    }
    sm[t] = mx;
    __syncthreads();
    if (ro == 0) {
        f32x2 m0 = sm[t], m1 = sm[t + 64], m2 = sm[t + 128], m3 = sm[t + 192];
        m0.x = fmaxf(fmaxf(m0.x, m1.x), fmaxf(m2.x, m3.x));
        m0.y = fmaxf(fmaxf(m0.y, m1.y), fmaxf(m2.y, m3.y));
        *(f32x2*)(pool + g * DIM + c2) = m0;
    }
}

// ---------------- GEMM: OUT(bf16) = f(X(bf16)) @ W; LDS-transposed epilogue ----------------
// XFORM=0: f=identity.  XFORM=1: f=relu(a*x+b) per column.
// Epilogue stages fp32 tile halves in per-wave LDS, stores uint2 (4 full 128B lines/instr).
template <bool XFORM>
__global__ __launch_bounds__(256, 3) void k_gemm(const unsigned* __restrict__ X,
                                                 const short* __restrict__ wt,
                                                 const float* __restrict__ ab,
                                                 unsigned* __restrict__ OUT,
                                                 float* __restrict__ stats8) {
    __shared__ short wsh[128 * WPAD];       // 34816 B
    __shared__ float tbuf[4][16][68];       // 17408 B, per-wave transpose buffer
    __shared__ float smst[256];             // 1024 B
    const int tid = threadIdx.x;
    {   // stage W (32KB) with padded rows
        int n = tid >> 1, hh = tid & 1;
        const int4* g = (const int4*)(wt + n * 128 + hh * 64);
        int4* l = (int4*)(wsh + n * WPAD + hh * 64);
#pragma unroll
        for (int i = 0; i < 8; i++) l[i] = g[i];
    }
    smst[tid] = 0.f;
    __syncthreads();

    const int lane = tid & 63, wid = tid >> 6;
    const int ln15 = lane & 15, q = lane >> 4;
    float (*buf)[68] = tbuf[wid];

    float sac[8], qac[8];
#pragma unroll
    for (int t = 0; t < 8; t++) { sac[t] = 0.f; qac[t] = 0.f; }

    f32x4 aA[4], aB[4], bA[4], bB[4];
    if (XFORM) {
#pragma unroll
        for (int s = 0; s < 4; s++) {
            int k0 = s * 32 + q * 8;
            aA[s] = *(const f32x4*)(ab + k0);
            aB[s] = *(const f32x4*)(ab + k0 + 4);
            bA[s] = *(const f32x4*)(ab + DIM + k0);
            bB[s] = *(const f32x4*)(ab + DIM + k0 + 4);
        }
    }

    for (int tile = blockIdx.x * 4 + wid; tile < N_NODES / 16; tile += gridDim.x * 4) {
        const unsigned* xr = X + (tile * 16 + ln15) * 64;  // u32 row of 64
        bf16x8 afr[4];
        if constexpr (!XFORM) {
#pragma unroll
            for (int s = 0; s < 4; s++)
                afr[s] = *(const bf16x8*)(xr + s * 16 + q * 4);
        } else {
#pragma unroll
            for (int s = 0; s < 4; s++) {
                uint4 wv = *(const uint4*)(xr + s * 16 + q * 4);
                float v0 = fmaxf(aA[s].x * bu2f(wv.x & 0xffffu) + bA[s].x, 0.f);
                float v1 = fmaxf(aA[s].y * bu2f(wv.x >> 16) + bA[s].y, 0.f);
                float v2 = fmaxf(aA[s].z * bu2f(wv.y & 0xffffu) + bA[s].z, 0.f);
                float v3 = fmaxf(aA[s].w * bu2f(wv.y >> 16) + bA[s].w, 0.f);
                float v4 = fmaxf(aB[s].x * bu2f(wv.z & 0xffffu) + bB[s].x, 0.f);
                float v5 = fmaxf(aB[s].y * bu2f(wv.z >> 16) + bB[s].y, 0.f);
                float v6 = fmaxf(aB[s].z * bu2f(wv.w & 0xffffu) + bB[s].z, 0.f);
                float v7 = fmaxf(aB[s].w * bu2f(wv.w >> 16) + bB[s].w, 0.f);
                bf16x8 a;
                a[0] = f2bs(v0); a[1] = f2bs(v1); a[2] = f2bs(v2); a[3] = f2bs(v3);
                a[4] = f2bs(v4); a[5] = f2bs(v5); a[6] = f2bs(v6); a[7] = f2bs(v7);
                afr[s] = a;
            }
        }
        f32x4 acc[8];
#pragma unroll
        for (int t = 0; t < 8; t++) acc[t] = (f32x4){0.f, 0.f, 0.f, 0.f};
#pragma unroll
        for (int s = 0; s < 4; s++) {
#pragma unroll
            for (int t = 0; t < 8; t++) {
                bf16x8 bfr = *(const bf16x8*)(wsh + (t * 16 + ln15) * WPAD + s * 32 + q * 8);
                acc[t] = __builtin_amdgcn_mfma_f32_16x16x32_bf16(afr[s], bfr, acc[t], 0, 0, 0);
            }
        }
        // stats (on fp32 accum, pre-rounding)
#pragma unroll
        for (int t = 0; t < 8; t++) {
            float s_l = 0.f, q_l = 0.f;
#pragma unroll
            for (int r = 0; r < 4; r++) {
                float v = acc[t][r];
                s_l += v;
                q_l += v * v;
            }
            s_l += __shfl_xor(s_l, 16); s_l += __shfl_xor(s_l, 32);
            q_l += __shfl_xor(q_l, 16); q_l += __shfl_xor(q_l, 32);
            sac[t] += s_l;
            qac[t] += q_l;
        }
        // epilogue: two 64-col halves through per-wave LDS transpose
#pragma unroll
        for (int ch = 0; ch < 2; ch++) {
#pragma unroll
            for (int t2 = 0; t2 < 4; t2++) {
                int t = ch * 4 + t2;
#pragma unroll
                for (int r = 0; r < 4; r++)
                    buf[q * 4 + r][t2 * 16 + ln15] = acc[t][r];
            }
#pragma unroll
            for (int rr = 0; rr < 4; rr++) {
                int lr = rr * 4 + q;
                f32x4 v = *(const f32x4*)&buf[lr][ln15 * 4];
                uint2 pp;
                pp.x = packbf(v.x, v.y);
                pp.y = packbf(v.z, v.w);
                *(uint2*)(OUT + (tile * 16 + lr) * 64 + ch * 32 + ln15 * 2) = pp;
            }
        }
    }
    if (lane < 16) {
#pragma unroll
        for (int t = 0; t < 8; t++) {
            atomicAdd(&smst[t * 16 + ln15], sac[t]);
            atomicAdd(&smst[128 + t * 16 + ln15], qac[t]);
        }
    }
    __syncthreads();
    atomicAdd(stats8 + (blockIdx.x & 7) * 256 + tid, smst[tid]);
}

// ---------------- fold BN stats (8 replicas) into a,b; reset ----------------
__global__ void k_bnfin(float* __restrict__ stats8, const float* __restrict__ gamma,
                        const float* __restrict__ beta, float* __restrict__ ab) {
    int c = threadIdx.x;  // 128
    float s = 0.f, sq = 0.f;
#pragma unroll
    for (int j = 0; j < 8; j++) {
        s += stats8[j * 256 + c];
        sq += stats8[j * 256 + 128 + c];
        stats8[j * 256 + c] = 0.f;
        stats8[j * 256 + 128 + c] = 0.f;
    }
    float mean = s * (1.f / N_NODES);
    float var = sq * (1.f / N_NODES) - mean * mean;
    float a = gamma[c] * rsqrtf(var + BN_EPS);
    ab[c] = a;
    ab[DIM + c] = beta[c] - mean * a;
}

// ---------------- H = relu(a*Zraw+b) (bf16), segmented pool ----------------
__global__ __launch_bounds__(256) void k_bnpool(const unsigned* __restrict__ Zb,
                                                const float* __restrict__ ab,
                                                const int* __restrict__ gs,
                                                const int* __restrict__ ge,
                                                unsigned* __restrict__ H,
                                                float* __restrict__ pool) {
    __shared__ f32x2 sm[256];
    int g = blockIdx.x, t = threadIdx.x;
    int ci = t & 63, ro = t >> 6;
    int beg = gs[g], end = ge[g];
    f32x2 a = *(const f32x2*)(ab + ci * 2);
    f32x2 b = *(const f32x2*)(ab + DIM + ci * 2);
    f32x2 mx = (f32x2){-3.402823e38f, -3.402823e38f};
    for (int r = beg + ro; r < end; r += 4) {
        unsigned w = Zb[r * 64 + ci];
        float vx = fmaxf(a.x * bu2f(w & 0xffffu) + b.x, 0.f);
        float vy = fmaxf(a.y * bu2f(w >> 16) + b.y, 0.f);
        H[r * 64 + ci] = packbf(vx, vy);
        mx.x = fmaxf(mx.x, vx);
        mx.y = fmaxf(mx.y, vy);
    }
    sm[t] = mx;
    __syncthreads();
    if (ro == 0) {
        f32x2 m0 = sm[t], m1 = sm[t + 64], m2 = sm[t + 128], m3 = sm[t + 192];
        m0.x = fmaxf(fmaxf(m0.x, m1.x), fmaxf(m2.x, m3.x));
        m0.y = fmaxf(fmaxf(m0.y, m1.y), fmaxf(m2.y, m3.y));
        *(f32x2*)(pool + g * DIM + ci * 2) = m0;
    }
}

// ---------------- score[g] = sum_l pooled[l][g] @ predW[l] + predb[l] ----------------
__global__ void k_readout(const float* __restrict__ pool, const float* __restrict__ predW,
                          const float* __restrict__ predb, float* __restrict__ out) {
    __shared__ float pl[5][DIM];
    int g = blockIdx.x, c = threadIdx.x;
    for (int l = 0; l < 5; l++) pl[l][c] = pool[l * N_GRAPHS * DIM + g * DIM + c];
    __syncthreads();
    float acc = 0.f;
    for (int l = 0; l < 5; l++) {
        acc += predb[l * DIM + c];
        const float* W = predW + l * DIM * DIM;
#pragma unroll 8
        for (int k = 0; k < DIM; k++) acc += pl[l][k] * W[k * DIM + c];
    }
    out[g * DIM + c] = acc;
}

extern "C" void kernel_launch(void* const* d_in, const int* in_sizes, int n_in,
                              void* d_out, int out_size, void* d_ws, size_t ws_size,
                              hipStream_t stream) {
    const float* h_in = (const float*)d_in[0];
    const int* src = (const int*)d_in[1];
    const int* dst = (const int*)d_in[2];
    const int* gid = (const int*)d_in[3];
    const float* W1s = (const float*)d_in[4];
    const float* W2s = (const float*)d_in[5];
    const float* bn1g = (const float*)d_in[6];
    const float* bn1b = (const float*)d_in[7];
    const float* bn2g = (const float*)d_in[8];
    const float* bn2b = (const float*)d_in[9];
    const float* predW = (const float*)d_in[10];
    const float* predb = (const float*)d_in[11];

    char* ws = (char*)d_ws;
    unsigned* hb = (unsigned*)(ws);                 // 12,800,000
    unsigned* Zb = (unsigned*)(ws + 12800000);      // 12,800,000
    unsigned* Yb = (unsigned*)(ws + 25600000);      // 12,800,000
    unsigned* H  = (unsigned*)(ws + 38400000);      // 12,800,000
    short* wt = (short*)(ws + 51200000);            // 262,144
    float* stats8 = (float*)(ws + 51462144);        // 8,192
    float* ab1 = (float*)(ws + 51470336);           // 1,024
    float* ab2 = (float*)(ws + 51471360);           // 1,024
    float* pool = (float*)(ws + 51472384);          // 1,310,720
    int* deg = (int*)(ws + 52783104);               // 200,000
    int* cursor = (int*)(ws + 52983104);            // 200,000
    int* toff = (int*)(ws + 53183104);              // 200,192
    int* bsum = (int*)(ws + 53383296);              // 1,024
    int* eix = (int*)(ws + 53384320);               // 3,200,000
    int* gs = (int*)(ws + 56584320);                // 2,048
    int* ge = (int*)(ws + 56586368);                // 2,048  (end: 56,588,416)

    k_init<<<NB_SCAN, 256, 0, stream>>>(stats8, deg, cursor, gs, ge);
    k_prep_w<<<512, 256, 0, stream>>>(W1s, W2s, wt);
    k_prep_h<<<12500, 256, 0, stream>>>(h_in, hb);
    k_ranges<<<NB_SCAN, 256, 0, stream>>>(gid, gs, ge);
    k_hist<<<3125, 256, 0, stream>>>(dst, deg);
    k_scan1<<<NB_SCAN, 256, 0, stream>>>(deg, toff, bsum);
    k_scan2<<<1, 256, 0, stream>>>(bsum);
    k_scan3<<<NB_SCAN, 256, 0, stream>>>(toff, bsum);
    k_fill<<<3125, 256, 0, stream>>>(src, dst, toff, cursor, eix);
    k_pool0seg<<<N_GRAPHS, 256, 0, stream>>>(h_in, gs, ge, pool);

    for (int l = 0; l < NLAYERS; l++) {
        const unsigned* hp = (l == 0) ? hb : H;
        k_gather<<<12500, 256, 0, stream>>>(hp, toff, deg, eix, Zb);
        k_gemm<false><<<782, 256, 0, stream>>>(Zb, wt + l * 16384, ab1, Yb, stats8);
        k_bnfin<<<1, 128, 0, stream>>>(stats8, bn1g + l * DIM, bn1b + l * DIM, ab1);
        k_gemm<true><<<782, 256, 0, stream>>>(Yb, wt + (4 + l) * 16384, ab1, Zb, stats8);
        k_bnfin<<<1, 128, 0, stream>>>(stats8, bn2g + l * DIM, bn2b + l * DIM, ab2);
        k_bnpool<<<N_GRAPHS, 256, 0, stream>>>(Zb, ab2, gs, ge, H, pool + (l + 1) * N_GRAPHS * DIM);
    }
    k_readout<<<512, 128, 0, stream>>>(pool, predW, predb, (float*)d_out);
}